// Round 6
// baseline (792.972 us; speedup 1.0000x reference)
//
#include <hip/hip_runtime.h>
#include <hip/hip_bf16.h>

// B=64, T=21, E=H=512, V=10000. fp32 in/out.
// gates = x@W_ih^T + h@W_hh^T + (b_ih+b_hh); i,f,g,o; out = h@W_lin^T + b_lin.

#define NB 64
#define NT 21
#define NE 512
#define NH 512
#define NV 10000
#define G4 2048

typedef __attribute__((ext_vector_type(8))) short bf16x8;
typedef __attribute__((ext_vector_type(4))) float f32x4;
typedef __attribute__((ext_vector_type(4))) unsigned short u16x4;

// ---- workspace layout (bytes) ----
#define OFF_WIH_HI   0UL
#define OFF_WIH_LO   2097152UL
#define OFF_WHH_HI   4194304UL
#define OFF_WHH_LO   6291456UL
#define OFF_WLIN_HI  8388608UL     // 10112*512*2
#define OFF_XSEQ_HI  18743296UL    // 1408*512*2
#define OFF_XSEQ_LO  20185088UL
#define OFF_BIAS     21626880UL    // 2048*4
#define OFF_XIH      21635072UL    // 21*64*2048*4
#define OFF_HPK      32645120UL    // 2 x 64*512 u32 (packed hi<<16|lo)
#define OFF_C        32907264UL    // 64*512 f32
#define OFF_HBUF     33038336UL    // 20*64*512 bf16
#define OFF_FLG      34349056UL    // per-step barrier counters
// end 34,351,616 B

__device__ inline unsigned short f2bf(float f) {
    unsigned int u = __float_as_uint(f);
    unsigned int r = u + 0x7FFFu + ((u >> 16) & 1u);
    return (unsigned short)(r >> 16);
}
__device__ inline float bf2f(unsigned short s) {
    return __uint_as_float(((unsigned int)s) << 16);
}

__device__ __forceinline__ void gl_lds16(const unsigned short* g, unsigned short* l) {
    auto gp = (const __attribute__((address_space(1))) unsigned int*)(unsigned long long)(const void*)g;
    auto lp = (__attribute__((address_space(3))) unsigned int*)(unsigned int)(unsigned long long)(void*)l;
    __builtin_amdgcn_global_load_lds(gp, lp, 16, 0, 0);
}

// ---------------- prep (vectorized x4) ----------------
// vec4 item ranges: W_ih [0,262144) W_hh [262144,524288) W_lin [524288,1804288)
// Xseq [1804288,1976320) bias [1976320,1976832). 1976832/256 = 7722 blocks.
__global__ __launch_bounds__(256) void prep_kernel(
    const float* __restrict__ features, const float* __restrict__ cap,
    const float* __restrict__ W_ih, const float* __restrict__ W_hh,
    const float* __restrict__ b_ih, const float* __restrict__ b_hh,
    const float* __restrict__ W_lin, unsigned char* __restrict__ ws)
{
    const int idx = blockIdx.x * 256 + threadIdx.x;
    unsigned short* wih_hi = (unsigned short*)(ws + OFF_WIH_HI);
    unsigned short* wih_lo = (unsigned short*)(ws + OFF_WIH_LO);
    unsigned short* whh_hi = (unsigned short*)(ws + OFF_WHH_HI);
    unsigned short* whh_lo = (unsigned short*)(ws + OFF_WHH_LO);
    unsigned short* wlin_hi = (unsigned short*)(ws + OFF_WLIN_HI);
    unsigned short* xs_hi = (unsigned short*)(ws + OFF_XSEQ_HI);
    unsigned short* xs_lo = (unsigned short*)(ws + OFF_XSEQ_LO);
    float* bias = (float*)(ws + OFF_BIAS);

    if (idx < 262144) {
        const int i4 = idx * 4;
        float4 w = *(const float4*)(W_ih + i4);
        u16x4 hi, lo;
        hi.x = f2bf(w.x); lo.x = f2bf(w.x - bf2f(hi.x));
        hi.y = f2bf(w.y); lo.y = f2bf(w.y - bf2f(hi.y));
        hi.z = f2bf(w.z); lo.z = f2bf(w.z - bf2f(hi.z));
        hi.w = f2bf(w.w); lo.w = f2bf(w.w - bf2f(hi.w));
        *(u16x4*)(wih_hi + i4) = hi;
        *(u16x4*)(wih_lo + i4) = lo;
    } else if (idx < 524288) {
        const int i4 = (idx - 262144) * 4;
        float4 w = *(const float4*)(W_hh + i4);
        u16x4 hi, lo;
        hi.x = f2bf(w.x); lo.x = f2bf(w.x - bf2f(hi.x));
        hi.y = f2bf(w.y); lo.y = f2bf(w.y - bf2f(hi.y));
        hi.z = f2bf(w.z); lo.z = f2bf(w.z - bf2f(hi.z));
        hi.w = f2bf(w.w); lo.w = f2bf(w.w - bf2f(hi.w));
        *(u16x4*)(whh_hi + i4) = hi;
        *(u16x4*)(whh_lo + i4) = lo;
    } else if (idx < 1804288) {
        const int i4 = (idx - 524288) * 4;
        float4 w = *(const float4*)(W_lin + i4);
        u16x4 hi;
        hi.x = f2bf(w.x); hi.y = f2bf(w.y); hi.z = f2bf(w.z); hi.w = f2bf(w.w);
        *(u16x4*)(wlin_hi + i4) = hi;
    } else if (idx < 1976320) {
        const int i4 = (idx - 1804288) * 4;
        const int e = i4 & 511;
        const int b = (i4 >> 9) & 63;
        const int t = i4 >> 15;
        float4 x = (t == 0) ? *(const float4*)(features + b * NE + e)
                            : *(const float4*)(cap + b * (NT * NE) + (t - 1) * NE + e);
        u16x4 hi, lo;
        hi.x = f2bf(x.x); lo.x = f2bf(x.x - bf2f(hi.x));
        hi.y = f2bf(x.y); lo.y = f2bf(x.y - bf2f(hi.y));
        hi.z = f2bf(x.z); lo.z = f2bf(x.z - bf2f(hi.z));
        hi.w = f2bf(x.w); lo.w = f2bf(x.w - bf2f(hi.w));
        *(u16x4*)(xs_hi + i4) = hi;
        *(u16x4*)(xs_lo + i4) = lo;
    } else if (idx < 1976832) {
        const int j = (idx - 1976320) * 4;
        float4 a = *(const float4*)(b_ih + j);
        float4 b = *(const float4*)(b_hh + j);
        *(float4*)(bias + j) = make_float4(a.x + b.x, a.y + b.y, a.z + b.z, a.w + b.w);
    }
}

// ---------------- phase A: Xih = Xseq @ W_ih^T + bias, hi/lo 3-pass, tiled ----------------
__global__ __launch_bounds__(256) void gemm_a_kernel(unsigned char* __restrict__ ws)
{
    __shared__ unsigned short Ah[2][4096], Al[2][4096], Bh[2][4096], Bl[2][4096];
    const int tid = threadIdx.x;
    const int lane = tid & 63, wv = tid >> 6;
    const int mf = lane & 15, kg = lane >> 4;
    const int mw = (wv >> 1) * 64, nw = (wv & 1) * 64;
    const int m0 = blockIdx.y * 128, n0 = blockIdx.x * 128;

    const unsigned short* __restrict__ xh = (const unsigned short*)(ws + OFF_XSEQ_HI);
    const unsigned short* __restrict__ xl = (const unsigned short*)(ws + OFF_XSEQ_LO);
    const unsigned short* __restrict__ wh = (const unsigned short*)(ws + OFF_WIH_HI);
    const unsigned short* __restrict__ wl = (const unsigned short*)(ws + OFF_WIH_LO);
    const float* __restrict__ bias = (const float*)(ws + OFF_BIAS);
    float* __restrict__ xih = (float*)(ws + OFF_XIH);

    f32x4 acc[4][4];
#pragma unroll
    for (int i = 0; i < 4; i++)
#pragma unroll
        for (int j = 0; j < 4; j++) acc[i][j] = (f32x4){0.f, 0.f, 0.f, 0.f};

    auto stage = [&](int buf, int k0) {
#pragma unroll
        for (int h = 0; h < 2; ++h) {
            int s = h * 256 + tid;
            int r = s >> 2, ks = (s & 3) * 8;
            gl_lds16(xh + (size_t)(m0 + r) * 512 + k0 + ks, &Ah[buf][s * 8]);
            gl_lds16(xl + (size_t)(m0 + r) * 512 + k0 + ks, &Al[buf][s * 8]);
            gl_lds16(wh + (size_t)(n0 + r) * 512 + k0 + ks, &Bh[buf][s * 8]);
            gl_lds16(wl + (size_t)(n0 + r) * 512 + k0 + ks, &Bl[buf][s * 8]);
        }
    };

    stage(0, 0);
    for (int kt = 0; kt < 16; ++kt) {
        __syncthreads();
        const int cur = kt & 1;
        if (kt < 15) stage(cur ^ 1, (kt + 1) * 32);
        bf16x8 ah[4], al[4], bh[4], bl[4];
#pragma unroll
        for (int i = 0; i < 4; i++) {
            ah[i] = *(const bf16x8*)&Ah[cur][(mw + i * 16 + mf) * 32 + kg * 8];
            al[i] = *(const bf16x8*)&Al[cur][(mw + i * 16 + mf) * 32 + kg * 8];
            bh[i] = *(const bf16x8*)&Bh[cur][(nw + i * 16 + mf) * 32 + kg * 8];
            bl[i] = *(const bf16x8*)&Bl[cur][(nw + i * 16 + mf) * 32 + kg * 8];
        }
#pragma unroll
        for (int i = 0; i < 4; i++)
#pragma unroll
            for (int j = 0; j < 4; j++) {
                acc[i][j] = __builtin_amdgcn_mfma_f32_16x16x32_bf16(ah[i], bh[j], acc[i][j], 0, 0, 0);
                acc[i][j] = __builtin_amdgcn_mfma_f32_16x16x32_bf16(ah[i], bl[j], acc[i][j], 0, 0, 0);
                acc[i][j] = __builtin_amdgcn_mfma_f32_16x16x32_bf16(al[i], bh[j], acc[i][j], 0, 0, 0);
            }
    }
#pragma unroll
    for (int i = 0; i < 4; i++)
#pragma unroll
        for (int j = 0; j < 4; j++) {
            const int col = n0 + nw + j * 16 + mf;
            const float bb = bias[col];
#pragma unroll
            for (int r = 0; r < 4; r++) {
                const int R = m0 + mw + i * 16 + kg * 4 + r;
                if (R < NT * NB) xih[(size_t)R * G4 + col] = acc[i][j][r] + bb;
            }
        }
}

// ---------------- phase B: persistent LSTM, register-resident weights ----------------
// 32 blocks x 512 thr (8 waves = 4 quadrants x 2 k-halves, 2 waves/SIMD).
// W_hh hi+lo fragments preloaded into registers ONCE (constant across steps) ->
// the per-step MFMA loop touches global ONLY via one parallel burst of 32
// independent u64 atomic h-loads per phase (4 phases). No global loads gate
// the inner MFMAs. k-split reduction + gate exchange via 32 KB LDS.
__global__ __launch_bounds__(512) void lstm_persistent(unsigned char* __restrict__ ws)
{
    __shared__ float scr[4 * 4 * 64 * 4];   // 16 KB: k-split partials
    __shared__ float gl[4 * 64 * 16];       // 16 KB: gates [gate][row][ci]
    const int tid = threadIdx.x;
    const int lane = tid & 63, wv = tid >> 6;
    const int mf = lane & 15, kg = lane >> 4;
    const int q = wv & 3;        // gate quadrant
    const int ks = wv >> 2;      // k-half (0,1)
    const int bc = blockIdx.x;

    unsigned int* __restrict__ hpk = (unsigned int*)(ws + OFF_HPK);
    const unsigned short* __restrict__ whh_hi = (const unsigned short*)(ws + OFF_WHH_HI);
    const unsigned short* __restrict__ whh_lo = (const unsigned short*)(ws + OFF_WHH_LO);
    const float* __restrict__ xih_base = (const float*)(ws + OFF_XIH);
    float* __restrict__ cbuf = (float*)(ws + OFF_C);
    unsigned short* __restrict__ hbuf = (unsigned short*)(ws + OFF_HBUF);
    unsigned int* __restrict__ ctr = (unsigned int*)(ws + OFF_FLG);

    // ---- preload W_hh fragments for this wave's (col=q*512+bc*16+mf, k-half ks) ----
    bf16x8 bh[8], blo[8];
#pragma unroll
    for (int j = 0; j < 8; ++j) {
        const size_t off = (size_t)(q * 512 + bc * 16 + mf) * 512 + ks * 256 + j * 32 + kg * 8;
        bh[j] = *(const bf16x8*)(whh_hi + off);
        blo[j] = *(const bf16x8*)(whh_lo + off);
    }

    for (int t = 0; t < NT; ++t) {
        f32x4 acc[4];
#pragma unroll
        for (int m = 0; m < 4; m++) acc[m] = (f32x4){0.f, 0.f, 0.f, 0.f};

        if (t > 0) {
            const unsigned long long* __restrict__ hp64 =
                (const unsigned long long*)(hpk + ((t + 1) & 1) * (NB * NH));
#pragma unroll
            for (int p = 0; p < 4; ++p) {
                // burst: 32 independent u64 atomic loads (4 m-tiles x 2 k-iters x 4)
                unsigned long long d[4][2][4];
#pragma unroll
                for (int m = 0; m < 4; ++m)
#pragma unroll
                    for (int jj = 0; jj < 2; ++jj) {
                        const unsigned long long* src = hp64 +
                            (size_t)(m * 16 + mf) * 256 + ks * 128 + (p * 2 + jj) * 16 + kg * 4;
#pragma unroll
                        for (int w = 0; w < 4; ++w)
                            d[m][jj][w] = __hip_atomic_load(src + w, __ATOMIC_RELAXED,
                                                            __HIP_MEMORY_SCOPE_AGENT);
                    }
                // unpack + MFMA (weights already in registers)
#pragma unroll
                for (int m = 0; m < 4; ++m)
#pragma unroll
                    for (int jj = 0; jj < 2; ++jj) {
                        unsigned u0 = (unsigned)d[m][jj][0], u1 = (unsigned)(d[m][jj][0] >> 32);
                        unsigned u2 = (unsigned)d[m][jj][1], u3 = (unsigned)(d[m][jj][1] >> 32);
                        unsigned u4 = (unsigned)d[m][jj][2], u5 = (unsigned)(d[m][jj][2] >> 32);
                        unsigned u6 = (unsigned)d[m][jj][3], u7 = (unsigned)(d[m][jj][3] >> 32);
                        union { bf16x8 v; unsigned int u[4]; } Ahf, Alf;
                        Ahf.u[0] = __builtin_amdgcn_perm(u1, u0, 0x07060302u);
                        Ahf.u[1] = __builtin_amdgcn_perm(u3, u2, 0x07060302u);
                        Ahf.u[2] = __builtin_amdgcn_perm(u5, u4, 0x07060302u);
                        Ahf.u[3] = __builtin_amdgcn_perm(u7, u6, 0x07060302u);
                        Alf.u[0] = __builtin_amdgcn_perm(u1, u0, 0x05040100u);
                        Alf.u[1] = __builtin_amdgcn_perm(u3, u2, 0x05040100u);
                        Alf.u[2] = __builtin_amdgcn_perm(u5, u4, 0x05040100u);
                        Alf.u[3] = __builtin_amdgcn_perm(u7, u6, 0x05040100u);
                        const int j = p * 2 + jj;
                        acc[m] = __builtin_amdgcn_mfma_f32_16x16x32_bf16(Ahf.v, bh[j], acc[m], 0, 0, 0);
                        acc[m] = __builtin_amdgcn_mfma_f32_16x16x32_bf16(Ahf.v, blo[j], acc[m], 0, 0, 0);
                        acc[m] = __builtin_amdgcn_mfma_f32_16x16x32_bf16(Alf.v, bh[j], acc[m], 0, 0, 0);
                    }
                __builtin_amdgcn_sched_barrier(0);  // keep phases' bursts from merging (VGPR)
            }
        }

        // ---- k-split reduction (ks=1 -> LDS -> ks=0) ----
        if (ks == 1) {
#pragma unroll
            for (int m = 0; m < 4; ++m)
                *(f32x4*)&scr[((q * 4 + m) * 64 + lane) * 4] = acc[m];
        }
        __syncthreads();
        if (ks == 0) {
#pragma unroll
            for (int m = 0; m < 4; ++m) {
                f32x4 o = *(const f32x4*)&scr[((q * 4 + m) * 64 + lane) * 4];
                acc[m] += o;
#pragma unroll
                for (int r = 0; r < 4; ++r)
                    gl[(q * 64 + m * 16 + kg * 4 + r) * 16 + mf] = acc[m][r];
            }
        }
        __syncthreads();

        // ---- LSTM cell: 1024 cells over 512 threads ----
        unsigned int* __restrict__ hpw = hpk + (t & 1) * (NB * NH);
        const float* __restrict__ xih = xih_base + (size_t)t * NB * G4;
#pragma unroll
        for (int cc = 0; cc < 2; ++cc) {
            const int cidx = cc * 512 + tid;
            const int row = cidx >> 4, ci = cidx & 15;
            const int c = bc * 16 + ci;
            const float gi = gl[(0 * 64 + row) * 16 + ci] + xih[row * G4 + 0 * 512 + c];
            const float gf = gl[(1 * 64 + row) * 16 + ci] + xih[row * G4 + 1 * 512 + c];
            const float gg = gl[(2 * 64 + row) * 16 + ci] + xih[row * G4 + 2 * 512 + c];
            const float go = gl[(3 * 64 + row) * 16 + ci] + xih[row * G4 + 3 * 512 + c];
            const float i_ = 1.f / (1.f + __expf(-gi));
            const float f_ = 1.f / (1.f + __expf(-gf));
            const float g_ = tanhf(gg);
            const float o_ = 1.f / (1.f + __expf(-go));
            const float c_old = (t == 0) ? 0.f : cbuf[row * NH + c];
            const float c_new = f_ * c_old + i_ * g_;
            cbuf[row * NH + c] = c_new;
            const float h_new = o_ * tanhf(c_new);
            const unsigned int hi = f2bf(h_new);
            const unsigned int lo = f2bf(h_new - bf2f((unsigned short)hi));
            __hip_atomic_store(&hpw[row * NH + c], (hi << 16) | lo,
                               __ATOMIC_RELAXED, __HIP_MEMORY_SCOPE_AGENT);
            if (t >= 1) hbuf[(t - 1) * (NB * NH) + row * NH + c] = (unsigned short)hi;
        }

        if (t < NT - 1) {
            // __syncthreads drains vmcnt -> h stores at coherence point before arrival.
            __syncthreads();
            if (tid == 0) {
                atomicAdd(&ctr[t], 1u);
                while (atomicAdd(&ctr[t], 0u) < (unsigned)gridDim.x)
                    __builtin_amdgcn_s_sleep(1);
            }
            __syncthreads();
        }
    }
}

// ---------------- phase C: Out = Hbuf[1280x512] @ W_lin^T + b_lin, tiled ----------------
__global__ __launch_bounds__(256) void gemm_c_kernel(
    unsigned char* __restrict__ ws, const float* __restrict__ b_lin, float* __restrict__ out)
{
    __shared__ unsigned short As[2][4096], Bs[2][4096];
    const int tid = threadIdx.x;
    const int lane = tid & 63, wv = tid >> 6;
    const int mf = lane & 15, kg = lane >> 4;
    const int mw = (wv >> 1) * 64, nw = (wv & 1) * 64;
    const int m0 = blockIdx.y * 128, n0 = blockIdx.x * 128;

    const unsigned short* __restrict__ hb = (const unsigned short*)(ws + OFF_HBUF);
    const unsigned short* __restrict__ wlin = (const unsigned short*)(ws + OFF_WLIN_HI);

    f32x4 acc[4][4];
#pragma unroll
    for (int i = 0; i < 4; i++)
#pragma unroll
        for (int j = 0; j < 4; j++) acc[i][j] = (f32x4){0.f, 0.f, 0.f, 0.f};

    auto stage = [&](int buf, int k0) {
#pragma unroll
        for (int h = 0; h < 2; ++h) {
            int s = h * 256 + tid;
            int r = s >> 2, ks = (s & 3) * 8;
            gl_lds16(hb + (size_t)(m0 + r) * 512 + k0 + ks, &As[buf][s * 8]);
            gl_lds16(wlin + (size_t)(n0 + r) * 512 + k0 + ks, &Bs[buf][s * 8]);
        }
    };

    stage(0, 0);
    for (int kt = 0; kt < 16; ++kt) {
        __syncthreads();
        const int cur = kt & 1;
        if (kt < 15) stage(cur ^ 1, (kt + 1) * 32);
        bf16x8 af[4], bf[4];
#pragma unroll
        for (int i = 0; i < 4; i++) {
            af[i] = *(const bf16x8*)&As[cur][(mw + i * 16 + mf) * 32 + kg * 8];
            bf[i] = *(const bf16x8*)&Bs[cur][(nw + i * 16 + mf) * 32 + kg * 8];
        }
#pragma unroll
        for (int i = 0; i < 4; i++)
#pragma unroll
            for (int j = 0; j < 4; j++)
                acc[i][j] = __builtin_amdgcn_mfma_f32_16x16x32_bf16(af[i], bf[j], acc[i][j], 0, 0, 0);
    }
#pragma unroll
    for (int i = 0; i < 4; i++)
#pragma unroll
        for (int j = 0; j < 4; j++) {
            const int col = n0 + nw + j * 16 + mf;
            if (col < NV) {
                const float bl = b_lin[col];
#pragma unroll
                for (int r = 0; r < 4; r++) {
                    const int R = m0 + mw + i * 16 + kg * 4 + r;  // = t*64 + b
                    const int b_ = R & 63, tt = R >> 6;
                    out[(size_t)b_ * ((NT - 1) * NV) + (size_t)tt * NV + col] = acc[i][j][r] + bl;
                }
            }
        }
}

extern "C" void kernel_launch(void* const* d_in, const int* in_sizes, int n_in,
                              void* d_out, int out_size, void* d_ws, size_t ws_size,
                              hipStream_t stream)
{
    const float* features = (const float*)d_in[0];
    const float* cap      = (const float*)d_in[1];
    const float* W_ih     = (const float*)d_in[2];
    const float* W_hh     = (const float*)d_in[3];
    const float* b_ih     = (const float*)d_in[4];
    const float* b_hh     = (const float*)d_in[5];
    const float* W_lin    = (const float*)d_in[6];
    const float* b_lin    = (const float*)d_in[7];
    float* out = (float*)d_out;
    unsigned char* ws = (unsigned char*)d_ws;

    hipMemsetAsync(ws + OFF_FLG, 0, (NT - 1) * sizeof(unsigned int), stream);

    hipLaunchKernelGGL(prep_kernel, dim3(7722), dim3(256), 0, stream,
                       features, cap, W_ih, W_hh, b_ih, b_hh, W_lin, ws);
    hipLaunchKernelGGL(gemm_a_kernel, dim3(16, 11), dim3(256), 0, stream, ws);
    hipLaunchKernelGGL(lstm_persistent, dim3(32), dim3(512), 0, stream, ws);
    hipLaunchKernelGGL(gemm_c_kernel, dim3(79, 10), dim3(256), 0, stream, ws, b_lin, out);
}

// Round 7
// 484.551 us; speedup vs baseline: 1.6365x; 1.6365x over previous
//
#include <hip/hip_runtime.h>
#include <hip/hip_bf16.h>

// B=64, T=21, E=H=512, V=10000. fp32 in/out.
// gates = x@W_ih^T + h@W_hh^T + (b_ih+b_hh); i,f,g,o; out = h@W_lin^T + b_lin.

#define NB 64
#define NT 21
#define NE 512
#define NH 512
#define NV 10000
#define G4 2048

typedef __attribute__((ext_vector_type(8))) short bf16x8;
typedef __attribute__((ext_vector_type(4))) float f32x4;
typedef __attribute__((ext_vector_type(4))) unsigned short u16x4;

// ---- workspace layout (bytes) ----
#define OFF_WIH_HI   0UL
#define OFF_WIH_LO   2097152UL
#define OFF_WHH_HI   4194304UL
#define OFF_WHH_LO   6291456UL
#define OFF_WLIN_HI  8388608UL     // 10112*512*2
#define OFF_XSEQ_HI  18743296UL    // 1408*512*2
#define OFF_XSEQ_LO  20185088UL
#define OFF_BIAS     21626880UL    // 2048*4
#define OFF_XIH      21635072UL    // 21*64*2048*4
#define OFF_GHH      32645120UL    // 2 x 64*512 bf16 h-hi (PRE-SWIZZLED chunk layout)
#define OFF_GHL      32776192UL    // 2 x 64*512 bf16 h-lo (linear)
#define OFF_C        32907264UL    // 64*512 f32
#define OFF_HBUF     33038336UL    // 20*64*512 bf16
#define OFF_FLG      34349056UL    // per-step barrier counters
// end 34,351,616 B

__device__ inline unsigned short f2bf(float f) {
    unsigned int u = __float_as_uint(f);
    unsigned int r = u + 0x7FFFu + ((u >> 16) & 1u);
    return (unsigned short)(r >> 16);
}
__device__ inline float bf2f(unsigned short s) {
    return __uint_as_float(((unsigned int)s) << 16);
}

__device__ __forceinline__ void gl_lds16(const unsigned short* g, unsigned short* l) {
    auto gp = (const __attribute__((address_space(1))) unsigned int*)(unsigned long long)(const void*)g;
    auto lp = (__attribute__((address_space(3))) unsigned int*)(unsigned int)(unsigned long long)(void*)l;
    __builtin_amdgcn_global_load_lds(gp, lp, 16, 0, 0);
}

// ---------------- prep (vectorized x4) ----------------
__global__ __launch_bounds__(256) void prep_kernel(
    const float* __restrict__ features, const float* __restrict__ cap,
    const float* __restrict__ W_ih, const float* __restrict__ W_hh,
    const float* __restrict__ b_ih, const float* __restrict__ b_hh,
    const float* __restrict__ W_lin, unsigned char* __restrict__ ws)
{
    const int idx = blockIdx.x * 256 + threadIdx.x;
    unsigned short* wih_hi = (unsigned short*)(ws + OFF_WIH_HI);
    unsigned short* wih_lo = (unsigned short*)(ws + OFF_WIH_LO);
    unsigned short* whh_hi = (unsigned short*)(ws + OFF_WHH_HI);
    unsigned short* whh_lo = (unsigned short*)(ws + OFF_WHH_LO);
    unsigned short* wlin_hi = (unsigned short*)(ws + OFF_WLIN_HI);
    unsigned short* xs_hi = (unsigned short*)(ws + OFF_XSEQ_HI);
    unsigned short* xs_lo = (unsigned short*)(ws + OFF_XSEQ_LO);
    float* bias = (float*)(ws + OFF_BIAS);

    if (idx < 262144) {
        const int i4 = idx * 4;
        float4 w = *(const float4*)(W_ih + i4);
        u16x4 hi, lo;
        hi.x = f2bf(w.x); lo.x = f2bf(w.x - bf2f(hi.x));
        hi.y = f2bf(w.y); lo.y = f2bf(w.y - bf2f(hi.y));
        hi.z = f2bf(w.z); lo.z = f2bf(w.z - bf2f(hi.z));
        hi.w = f2bf(w.w); lo.w = f2bf(w.w - bf2f(hi.w));
        *(u16x4*)(wih_hi + i4) = hi;
        *(u16x4*)(wih_lo + i4) = lo;
    } else if (idx < 524288) {
        const int i4 = (idx - 262144) * 4;
        float4 w = *(const float4*)(W_hh + i4);
        u16x4 hi, lo;
        hi.x = f2bf(w.x); lo.x = f2bf(w.x - bf2f(hi.x));
        hi.y = f2bf(w.y); lo.y = f2bf(w.y - bf2f(hi.y));
        hi.z = f2bf(w.z); lo.z = f2bf(w.z - bf2f(hi.z));
        hi.w = f2bf(w.w); lo.w = f2bf(w.w - bf2f(hi.w));
        *(u16x4*)(whh_hi + i4) = hi;
        *(u16x4*)(whh_lo + i4) = lo;
    } else if (idx < 1804288) {
        const int i4 = (idx - 524288) * 4;
        float4 w = *(const float4*)(W_lin + i4);
        u16x4 hi;
        hi.x = f2bf(w.x); hi.y = f2bf(w.y); hi.z = f2bf(w.z); hi.w = f2bf(w.w);
        *(u16x4*)(wlin_hi + i4) = hi;
    } else if (idx < 1976320) {
        const int i4 = (idx - 1804288) * 4;
        const int e = i4 & 511;
        const int b = (i4 >> 9) & 63;
        const int t = i4 >> 15;
        float4 x = (t == 0) ? *(const float4*)(features + b * NE + e)
                            : *(const float4*)(cap + b * (NT * NE) + (t - 1) * NE + e);
        u16x4 hi, lo;
        hi.x = f2bf(x.x); lo.x = f2bf(x.x - bf2f(hi.x));
        hi.y = f2bf(x.y); lo.y = f2bf(x.y - bf2f(hi.y));
        hi.z = f2bf(x.z); lo.z = f2bf(x.z - bf2f(hi.z));
        hi.w = f2bf(x.w); lo.w = f2bf(x.w - bf2f(hi.w));
        *(u16x4*)(xs_hi + i4) = hi;
        *(u16x4*)(xs_lo + i4) = lo;
    } else if (idx < 1976832) {
        const int j = (idx - 1976320) * 4;
        float4 a = *(const float4*)(b_ih + j);
        float4 b = *(const float4*)(b_hh + j);
        *(float4*)(bias + j) = make_float4(a.x + b.x, a.y + b.y, a.z + b.z, a.w + b.w);
    }
}

// ---------------- phase A: Xih = Xseq @ W_ih^T + bias, hi/lo 3-pass, tiled ----------------
__global__ __launch_bounds__(256) void gemm_a_kernel(unsigned char* __restrict__ ws)
{
    __shared__ unsigned short Ah[2][4096], Al[2][4096], Bh[2][4096], Bl[2][4096];
    const int tid = threadIdx.x;
    const int lane = tid & 63, wv = tid >> 6;
    const int mf = lane & 15, kg = lane >> 4;
    const int mw = (wv >> 1) * 64, nw = (wv & 1) * 64;
    const int m0 = blockIdx.y * 128, n0 = blockIdx.x * 128;

    const unsigned short* __restrict__ xh = (const unsigned short*)(ws + OFF_XSEQ_HI);
    const unsigned short* __restrict__ xl = (const unsigned short*)(ws + OFF_XSEQ_LO);
    const unsigned short* __restrict__ wh = (const unsigned short*)(ws + OFF_WIH_HI);
    const unsigned short* __restrict__ wl = (const unsigned short*)(ws + OFF_WIH_LO);
    const float* __restrict__ bias = (const float*)(ws + OFF_BIAS);
    float* __restrict__ xih = (float*)(ws + OFF_XIH);

    f32x4 acc[4][4];
#pragma unroll
    for (int i = 0; i < 4; i++)
#pragma unroll
        for (int j = 0; j < 4; j++) acc[i][j] = (f32x4){0.f, 0.f, 0.f, 0.f};

    auto stage = [&](int buf, int k0) {
#pragma unroll
        for (int h = 0; h < 2; ++h) {
            int s = h * 256 + tid;
            int r = s >> 2, ks = (s & 3) * 8;
            gl_lds16(xh + (size_t)(m0 + r) * 512 + k0 + ks, &Ah[buf][s * 8]);
            gl_lds16(xl + (size_t)(m0 + r) * 512 + k0 + ks, &Al[buf][s * 8]);
            gl_lds16(wh + (size_t)(n0 + r) * 512 + k0 + ks, &Bh[buf][s * 8]);
            gl_lds16(wl + (size_t)(n0 + r) * 512 + k0 + ks, &Bl[buf][s * 8]);
        }
    };

    stage(0, 0);
    for (int kt = 0; kt < 16; ++kt) {
        __syncthreads();
        const int cur = kt & 1;
        if (kt < 15) stage(cur ^ 1, (kt + 1) * 32);
        bf16x8 ah[4], al[4], bh[4], bl[4];
#pragma unroll
        for (int i = 0; i < 4; i++) {
            ah[i] = *(const bf16x8*)&Ah[cur][(mw + i * 16 + mf) * 32 + kg * 8];
            al[i] = *(const bf16x8*)&Al[cur][(mw + i * 16 + mf) * 32 + kg * 8];
            bh[i] = *(const bf16x8*)&Bh[cur][(nw + i * 16 + mf) * 32 + kg * 8];
            bl[i] = *(const bf16x8*)&Bl[cur][(nw + i * 16 + mf) * 32 + kg * 8];
        }
#pragma unroll
        for (int i = 0; i < 4; i++)
#pragma unroll
            for (int j = 0; j < 4; j++) {
                acc[i][j] = __builtin_amdgcn_mfma_f32_16x16x32_bf16(ah[i], bh[j], acc[i][j], 0, 0, 0);
                acc[i][j] = __builtin_amdgcn_mfma_f32_16x16x32_bf16(ah[i], bl[j], acc[i][j], 0, 0, 0);
                acc[i][j] = __builtin_amdgcn_mfma_f32_16x16x32_bf16(al[i], bh[j], acc[i][j], 0, 0, 0);
            }
    }
#pragma unroll
    for (int i = 0; i < 4; i++)
#pragma unroll
        for (int j = 0; j < 4; j++) {
            const int col = n0 + nw + j * 16 + mf;
            const float bb = bias[col];
#pragma unroll
            for (int r = 0; r < 4; r++) {
                const int R = m0 + mw + i * 16 + kg * 4 + r;
                if (R < NT * NB) xih[(size_t)R * G4 + col] = acc[i][j][r] + bb;
            }
        }
}

// ---------------- phase B: persistent LSTM, plain-load h exchange ----------------
// 32 blocks x 512 thr (8 waves = 4 gate quadrants x 2 k-halves).
// W_hh hi+lo fragments in REGISTERS (loaded once, survive cache invalidates).
// Cross-step h: plain stores -> ONE release fence (buffer_wbl2) -> RMW barrier
// (relaxed, no per-poll cache ops) -> ONE acquire fence (buffer_inv) -> h-hi
// image DMA'd to LDS via global_load_lds (pre-swizzled in global so the linear
// DMA gives a conflict-free LDS image); h-lo streamed as plain pipelined loads.
__global__ __launch_bounds__(512) void lstm_persistent(unsigned char* __restrict__ ws)
{
    __shared__ unsigned short Hhi[64 * 512];   // 64 KB h-hi image; reused for reduction
    const int tid = threadIdx.x;
    const int lane = tid & 63, wv = tid >> 6;
    const int mf = lane & 15, kg = lane >> 4;
    const int q = wv & 3;        // gate quadrant
    const int ks = wv >> 2;      // k-half
    const int bc = blockIdx.x;

    unsigned short* __restrict__ ghh = (unsigned short*)(ws + OFF_GHH);
    unsigned short* __restrict__ ghl = (unsigned short*)(ws + OFF_GHL);
    const unsigned short* __restrict__ whh_hi = (const unsigned short*)(ws + OFF_WHH_HI);
    const unsigned short* __restrict__ whh_lo = (const unsigned short*)(ws + OFF_WHH_LO);
    const float* __restrict__ xih_base = (const float*)(ws + OFF_XIH);
    float* __restrict__ cbuf = (float*)(ws + OFF_C);
    unsigned short* __restrict__ hbuf = (unsigned short*)(ws + OFF_HBUF);
    unsigned int* __restrict__ ctr = (unsigned int*)(ws + OFF_FLG);

    float* scrf = (float*)Hhi;           // 16 KB k-split partials (after MFMA)
    float* glf  = (float*)Hhi + 4096;    // 16 KB gate values

    // ---- preload W_hh hi+lo fragments: cols q*512+bc*16+mf, k-half ks ----
    bf16x8 bh[8], blo[8];
#pragma unroll
    for (int j = 0; j < 8; ++j) {
        const size_t off = (size_t)(q * 512 + bc * 16 + mf) * 512 + ks * 256 + j * 32 + kg * 8;
        bh[j] = *(const bf16x8*)(whh_hi + off);
        blo[j] = *(const bf16x8*)(whh_lo + off);
    }

    for (int t = 0; t < NT; ++t) {
        f32x4 acc[4];
#pragma unroll
        for (int m = 0; m < 4; m++) acc[m] = (f32x4){0.f, 0.f, 0.f, 0.f};

        if (t > 0) {
            const int rd = (t + 1) & 1;
            const unsigned short* __restrict__ ghh_r = ghh + rd * (NB * NH);
            const unsigned short* __restrict__ ghl_r = ghl + rd * (NB * NH);
            // ---- stage h-hi image (64 KB) into LDS: 8 DMA insts/thread ----
#pragma unroll
            for (int i = 0; i < 8; ++i) {
                const int s = i * 512 + tid;
                gl_lds16(ghh_r + s * 8, &Hhi[s * 8]);
            }
            __syncthreads();   // drains vmcnt incl. global_load_lds
            // ---- MFMA: A-hi from LDS (swizzled), A-lo plain global, B in regs ----
#pragma unroll
            for (int kt = 0; kt < 8; ++kt) {
                const int j = ks * 32 + kt * 4 + kg;   // 16B chunk index [0,64)
#pragma unroll
                for (int m = 0; m < 4; ++m) {
                    const int row = m * 16 + mf;
                    bf16x8 a_hi = *(const bf16x8*)&Hhi[(row * 64 + (j ^ (row & 7))) * 8];
                    bf16x8 a_lo = *(const bf16x8*)(ghl_r + row * 512 + j * 8);
                    acc[m] = __builtin_amdgcn_mfma_f32_16x16x32_bf16(a_hi, bh[kt], acc[m], 0, 0, 0);
                    acc[m] = __builtin_amdgcn_mfma_f32_16x16x32_bf16(a_hi, blo[kt], acc[m], 0, 0, 0);
                    acc[m] = __builtin_amdgcn_mfma_f32_16x16x32_bf16(a_lo, bh[kt], acc[m], 0, 0, 0);
                }
            }
            __syncthreads();   // h-image reads done before LDS reuse
        }

        // ---- k-split reduction via LDS (reusing Hhi region) ----
        if (ks == 1) {
#pragma unroll
            for (int m = 0; m < 4; ++m)
                *(f32x4*)&scrf[((q * 4 + m) * 64 + lane) * 4] = acc[m];
        }
        __syncthreads();
        if (ks == 0) {
#pragma unroll
            for (int m = 0; m < 4; ++m) {
                f32x4 o = *(const f32x4*)&scrf[((q * 4 + m) * 64 + lane) * 4];
                acc[m] += o;
#pragma unroll
                for (int r = 0; r < 4; ++r)
                    glf[(q * 64 + m * 16 + kg * 4 + r) * 16 + mf] = acc[m][r];
            }
        }
        __syncthreads();

        // ---- LSTM cell: 1024 cells over 512 threads ----
        unsigned short* __restrict__ ghh_w = ghh + (t & 1) * (NB * NH);
        unsigned short* __restrict__ ghl_w = ghl + (t & 1) * (NB * NH);
        const float* __restrict__ xih = xih_base + (size_t)t * NB * G4;
#pragma unroll
        for (int cc = 0; cc < 2; ++cc) {
            const int cidx = cc * 512 + tid;
            const int row = cidx >> 4, ci = cidx & 15;
            const int c = bc * 16 + ci;
            const float gi = glf[(0 * 64 + row) * 16 + ci] + xih[row * G4 + 0 * 512 + c];
            const float gf = glf[(1 * 64 + row) * 16 + ci] + xih[row * G4 + 1 * 512 + c];
            const float gg = glf[(2 * 64 + row) * 16 + ci] + xih[row * G4 + 2 * 512 + c];
            const float go = glf[(3 * 64 + row) * 16 + ci] + xih[row * G4 + 3 * 512 + c];
            const float i_ = 1.f / (1.f + __expf(-gi));
            const float f_ = 1.f / (1.f + __expf(-gf));
            const float g_ = tanhf(gg);
            const float o_ = 1.f / (1.f + __expf(-go));
            const float c_old = (t == 0) ? 0.f : cbuf[row * NH + c];
            const float c_new = f_ * c_old + i_ * g_;
            cbuf[row * NH + c] = c_new;
            const float h_new = o_ * tanhf(c_new);
            const unsigned short hi = f2bf(h_new);
            const unsigned short lo = f2bf(h_new - bf2f(hi));
            // h-hi: swizzled chunk layout (chunk j' = j ^ (row&7)); h-lo: linear
            const int j = c >> 3;
            ghh_w[row * 512 + ((j ^ (row & 7)) << 3) + (c & 7)] = hi;
            ghl_w[row * 512 + c] = lo;
            if (t >= 1) hbuf[(t - 1) * (NB * NH) + row * NH + c] = hi;
        }

        if (t < NT - 1) {
            __syncthreads();   // all threads' stores issued + vmcnt drained
            if (tid == 0) {
                __builtin_amdgcn_fence(__ATOMIC_RELEASE, "agent");  // one buffer_wbl2
                atomicAdd(&ctr[t], 1u);
                while (atomicAdd(&ctr[t], 0u) < 32u)
                    __builtin_amdgcn_s_sleep(1);
            }
            __syncthreads();
            __builtin_amdgcn_fence(__ATOMIC_ACQUIRE, "agent");      // one buffer_inv
        }
    }
}

// ---------------- phase C: Out = Hbuf[1280x512] @ W_lin^T + b_lin, tiled ----------------
__global__ __launch_bounds__(256) void gemm_c_kernel(
    unsigned char* __restrict__ ws, const float* __restrict__ b_lin, float* __restrict__ out)
{
    __shared__ unsigned short As[2][4096], Bs[2][4096];
    const int tid = threadIdx.x;
    const int lane = tid & 63, wv = tid >> 6;
    const int mf = lane & 15, kg = lane >> 4;
    const int mw = (wv >> 1) * 64, nw = (wv & 1) * 64;
    const int m0 = blockIdx.y * 128, n0 = blockIdx.x * 128;

    const unsigned short* __restrict__ hb = (const unsigned short*)(ws + OFF_HBUF);
    const unsigned short* __restrict__ wlin = (const unsigned short*)(ws + OFF_WLIN_HI);

    f32x4 acc[4][4];
#pragma unroll
    for (int i = 0; i < 4; i++)
#pragma unroll
        for (int j = 0; j < 4; j++) acc[i][j] = (f32x4){0.f, 0.f, 0.f, 0.f};

    auto stage = [&](int buf, int k0) {
#pragma unroll
        for (int h = 0; h < 2; ++h) {
            int s = h * 256 + tid;
            int r = s >> 2, ks = (s & 3) * 8;
            gl_lds16(hb + (size_t)(m0 + r) * 512 + k0 + ks, &As[buf][s * 8]);
            gl_lds16(wlin + (size_t)(n0 + r) * 512 + k0 + ks, &Bs[buf][s * 8]);
        }
    };

    stage(0, 0);
    for (int kt = 0; kt < 16; ++kt) {
        __syncthreads();
        const int cur = kt & 1;
        if (kt < 15) stage(cur ^ 1, (kt + 1) * 32);
        bf16x8 af[4], bf[4];
#pragma unroll
        for (int i = 0; i < 4; i++) {
            af[i] = *(const bf16x8*)&As[cur][(mw + i * 16 + mf) * 32 + kg * 8];
            bf[i] = *(const bf16x8*)&Bs[cur][(nw + i * 16 + mf) * 32 + kg * 8];
        }
#pragma unroll
        for (int i = 0; i < 4; i++)
#pragma unroll
            for (int j = 0; j < 4; j++)
                acc[i][j] = __builtin_amdgcn_mfma_f32_16x16x32_bf16(af[i], bf[j], acc[i][j], 0, 0, 0);
    }
#pragma unroll
    for (int i = 0; i < 4; i++)
#pragma unroll
        for (int j = 0; j < 4; j++) {
            const int col = n0 + nw + j * 16 + mf;
            if (col < NV) {
                const float bl = b_lin[col];
#pragma unroll
                for (int r = 0; r < 4; r++) {
                    const int R = m0 + mw + i * 16 + kg * 4 + r;  // = t*64 + b
                    const int b_ = R & 63, tt = R >> 6;
                    out[(size_t)b_ * ((NT - 1) * NV) + (size_t)tt * NV + col] = acc[i][j][r] + bl;
                }
            }
        }
}

extern "C" void kernel_launch(void* const* d_in, const int* in_sizes, int n_in,
                              void* d_out, int out_size, void* d_ws, size_t ws_size,
                              hipStream_t stream)
{
    const float* features = (const float*)d_in[0];
    const float* cap      = (const float*)d_in[1];
    const float* W_ih     = (const float*)d_in[2];
    const float* W_hh     = (const float*)d_in[3];
    const float* b_ih     = (const float*)d_in[4];
    const float* b_hh     = (const float*)d_in[5];
    const float* W_lin    = (const float*)d_in[6];
    const float* b_lin    = (const float*)d_in[7];
    float* out = (float*)d_out;
    unsigned char* ws = (unsigned char*)d_ws;

    hipMemsetAsync(ws + OFF_FLG, 0, (NT - 1) * sizeof(unsigned int), stream);

    hipLaunchKernelGGL(prep_kernel, dim3(7722), dim3(256), 0, stream,
                       features, cap, W_ih, W_hh, b_ih, b_hh, W_lin, ws);
    hipLaunchKernelGGL(gemm_a_kernel, dim3(16, 11), dim3(256), 0, stream, ws);
    hipLaunchKernelGGL(lstm_persistent, dim3(32), dim3(512), 0, stream, ws);
    hipLaunchKernelGGL(gemm_c_kernel, dim3(79, 10), dim3(256), 0, stream, ws, b_lin, out);
}